// Round 1
// baseline (81.057 us; speedup 1.0000x reference)
//
#include <hip/hip_runtime.h>

#define NPART 4096
#define CT    16
#define ALPHA 2.8f
// R_ONSET=1.7, R_CUTOFF=2.0 -> r_o^2=2.89, r_c^2=4.0, (r_c^2-r_o^2)^3 = 1.367631
#define R_ON   1.7f
#define R_C2   4.0f
#define INV_DEN (1.0f / 1.367631f)
#define TJ 64

// Kernel 1: per-particle prep.
//   w[i][d]  = sum_c ct[i,c] * 0.5*(E[i,c,d] + E[i,d,c])   (E_sym contraction)
//   maskv[i] = (sum_c ct[i,c] > 0) ? 1 : 0                  (column mask)
//   posr[i]  = {x, y, z, radius}
//   thread 0 zeroes the output accumulator (d_out is poisoned before each timed call)
__global__ __launch_bounds__(256) void prep_kernel(
        const float* __restrict__ pos,
        const float* __restrict__ ct,
        const float* __restrict__ eps,
        const float* __restrict__ rad,
        float* __restrict__ w,
        float* __restrict__ maskv,
        float4* __restrict__ posr,
        float* __restrict__ out) {
    int t = blockIdx.x * blockDim.x + threadIdx.x;  // 0 .. N*C-1
    int i = t >> 4;
    int d = t & 15;
    const float* Ei  = eps + i * (CT * CT);
    const float* cti = ct + i * CT;
    float acc = 0.f;
#pragma unroll
    for (int c = 0; c < CT; ++c)
        acc += cti[c] * 0.5f * (Ei[c * CT + d] + Ei[d * CT + c]);
    w[i * CT + d] = acc;
    if (d == 0) {
        float s = 0.f;
#pragma unroll
        for (int c = 0; c < CT; ++c) s += cti[c];
        maskv[i] = (s > 0.f) ? 1.f : 0.f;
        posr[i] = make_float4(pos[3 * i], pos[3 * i + 1], pos[3 * i + 2], rad[i]);
    }
    if (t == 0) *out = 0.f;
}

// Kernel 2: pair screen + rare-hit Morse energy.
// grid.x = N/256 (i blocks, one i per thread), grid.y = N/TJ (j chunks).
__global__ __launch_bounds__(256) void pair_kernel(
        const float4* __restrict__ posr,
        const float* __restrict__ ct,
        const float* __restrict__ w,
        const float* __restrict__ maskv,
        float* __restrict__ out) {
    __shared__ float4 tile[TJ];
    __shared__ float wsum_s[4];
    const int tid = threadIdx.x;
    const int i   = blockIdx.x * 256 + tid;
    const int j0  = blockIdx.y * TJ;

    if (tid < TJ) tile[tid] = posr[j0 + tid];
    const float4 pi = posr[i];
    __syncthreads();

    // screening pass: 64-bit hit mask (wave=64, TJ=64)
    unsigned long long hits = 0ull;
#pragma unroll 8
    for (int jj = 0; jj < TJ; ++jj) {
        float4 pj = tile[jj];
        float dx = pi.x - pj.x, dy = pi.y - pj.y, dz = pi.z - pj.z;
        float r2 = dx * dx + dy * dy + dz * dz;
        if ((j0 + jj) != i && r2 < R_C2) hits |= (1ull << jj);
    }

    float acc = 0.f;
    if (hits) {
        // i-side data only loaded on the ~3% of threads with a hit
        float cti[CT], wi[CT];
        const float4* ct4 = (const float4*)(ct + i * CT);
        const float4* w4  = (const float4*)(w + i * CT);
#pragma unroll
        for (int q = 0; q < 4; ++q) {
            float4 v = ct4[q];
            cti[4 * q] = v.x; cti[4 * q + 1] = v.y; cti[4 * q + 2] = v.z; cti[4 * q + 3] = v.w;
            float4 u = w4[q];
            wi[4 * q] = u.x; wi[4 * q + 1] = u.y; wi[4 * q + 2] = u.z; wi[4 * q + 3] = u.w;
        }
        while (hits) {
            int jj = __builtin_ctzll(hits);
            hits &= hits - 1;
            int j = j0 + jj;
            float4 pj = tile[jj];
            float dx = pi.x - pj.x, dy = pi.y - pj.y, dz = pi.z - pj.z;
            float r2 = dx * dx + dy * dy + dz * dz;
            float dr = sqrtf(r2 > 0.f ? r2 : 1.f);  // reference safe-sqrt semantics
            // smooth cutoff (dr < 2.0 guaranteed here, except r2==0 -> dr=1 < R_ON)
            float cut;
            if (dr < R_ON) {
                cut = 1.f;
            } else {
                float t1 = R_C2 - r2;                       // (r_c^2 - r^2)
                cut = t1 * t1 * (2.f * r2 - 4.67f) * INV_DEN; // (r_c^2 + 2r^2 - 3 r_o^2)
            }
            // bilinear eps: 0.5*(w_i . ct_j + w_j . ct_i)
            const float4* ctj4 = (const float4*)(ct + j * CT);
            const float4* wj4  = (const float4*)(w + j * CT);
            float a = 0.f, b = 0.f;
#pragma unroll
            for (int q = 0; q < 4; ++q) {
                float4 cv = ctj4[q];
                float4 wv = wj4[q];
                a += wi[4 * q] * cv.x + wi[4 * q + 1] * cv.y + wi[4 * q + 2] * cv.z + wi[4 * q + 3] * cv.w;
                b += cti[4 * q] * wv.x + cti[4 * q + 1] * wv.y + cti[4 * q + 2] * wv.z + cti[4 * q + 3] * wv.w;
            }
            float bb   = 0.5f * (a + b);
            float epsv = maskv[j] * (5.f / (1.f + __expf(-bb)) + 0.3f);
            float sigma = pi.w + pj.w;
            float u = 1.f - __expf(-ALPHA * (dr - sigma));
            acc += epsv * (u * u - 1.f) * cut;
        }
    }

    // wave(64) shuffle reduce -> LDS across 4 waves -> one atomic per block
#pragma unroll
    for (int off = 32; off; off >>= 1) acc += __shfl_down(acc, off, 64);
    int lane = tid & 63, wv = tid >> 6;
    if (lane == 0) wsum_s[wv] = acc;
    __syncthreads();
    if (tid == 0) atomicAdd(out, 0.5f * (wsum_s[0] + wsum_s[1] + wsum_s[2] + wsum_s[3]));
}

extern "C" void kernel_launch(void* const* d_in, const int* in_sizes, int n_in,
                              void* d_out, int out_size, void* d_ws, size_t ws_size,
                              hipStream_t stream) {
    const float* pos = (const float*)d_in[0];   // (N,3)
    const float* ct  = (const float*)d_in[1];   // (N,16)
    const float* eps = (const float*)d_in[2];   // (N,256)
    const float* rad = (const float*)d_in[3];   // (N,1)
    float* out = (float*)d_out;

    char* ws = (char*)d_ws;
    float*  w     = (float*)ws;                    // 4096*16*4 = 256 KB
    float4* posr  = (float4*)(ws + 256 * 1024);    // 4096*16  =  64 KB
    float*  maskv = (float*)(ws + 320 * 1024);     // 4096*4   =  16 KB

    prep_kernel<<<NPART * CT / 256, 256, 0, stream>>>(pos, ct, eps, rad, w, maskv, posr, out);
    dim3 grid(NPART / 256, NPART / TJ);            // (16, 64) = 1024 blocks
    pair_kernel<<<grid, 256, 0, stream>>>(posr, ct, w, maskv, out);
}